// Round 12
// baseline (302.973 us; speedup 1.0000x reference)
//
#include <hip/hip_runtime.h>
#include <cmath>

#define NN 50000
#define NE 800000
#define INF_ 128
#define NR 64
#define OF 128
#define TS 256
#define NT ((NN + TS - 1) / TS)  // 196 tiles

__device__ __forceinline__ unsigned short f2bf_rne(float f) {
  unsigned u = __float_as_uint(f);
  u += 0x7FFFu + ((u >> 16) & 1u);  // round-to-nearest-even
  return (unsigned short)(u >> 16);
}
__device__ __forceinline__ float bf2f(unsigned short h) {
  return __uint_as_float(((unsigned)h) << 16);
}

// zero cnt[] and the 64 ete_csr pad rows; block 0 also computes q3 = W3 @ a
__global__ void k_init(const float* __restrict__ W, const float* __restrict__ a,
                       float* __restrict__ q3, int* __restrict__ cnt,
                       unsigned* __restrict__ pad) {
  int i = blockIdx.x * 256 + threadIdx.x;
  if (i < NN) cnt[i] = 0;
  if (i < 2048) pad[i] = 0;  // 64 rows x 64 bf16 = 2048 uints, keep tv finite
  if (blockIdx.x == 0 && threadIdx.x < NR) {
    const float* row = W + (size_t)(2 * INF_ + threadIdx.x) * OF;
    float acc = 0.f;
    for (int j = 0; j < OF; ++j) acc = fmaf(row[j], a[j], acc);
    q3[threadIdx.x] = acc;
  }
}

// per-node precompute: xW1 = x@W1 (fp32), xw2h = x@W2 (bf16), p1, p2.
// Fused: src-degree histogram (grid*block == NE exactly, one edge per thread).
__global__ void k_node_pre(const float* __restrict__ x, const float* __restrict__ W,
                           const float* __restrict__ a, const int* __restrict__ ei,
                           float* __restrict__ xW1, unsigned short* __restrict__ xw2h,
                           float* __restrict__ p1, float* __restrict__ p2,
                           int* __restrict__ cnt) {
  int gid = blockIdx.x * 128 + threadIdx.x;  // 0..799999 == edge id
  atomicAdd(cnt + ei[gid], 1);
  __shared__ float xs[8][INF_];
  __shared__ float red[2][2][8];
  int nb = blockIdx.x * 8;
  int o = threadIdx.x;  // 0..127
  for (int t = 0; t < 8; ++t) xs[t][o] = x[(size_t)(nb + t) * INF_ + o];
  __syncthreads();
  float acc1[8] = {0.f, 0.f, 0.f, 0.f, 0.f, 0.f, 0.f, 0.f};
  float acc2[8] = {0.f, 0.f, 0.f, 0.f, 0.f, 0.f, 0.f, 0.f};
  for (int k = 0; k < INF_; ++k) {
    float w1 = W[(size_t)k * OF + o];
    float w2 = W[(size_t)(INF_ + k) * OF + o];
#pragma unroll
    for (int t = 0; t < 8; ++t) {
      acc1[t] = fmaf(xs[t][k], w1, acc1[t]);
      acc2[t] = fmaf(xs[t][k], w2, acc2[t]);
    }
  }
  float av = a[o];
  int wv = o >> 6, ln = o & 63;
#pragma unroll
  for (int t = 0; t < 8; ++t) {
    xW1[(size_t)(nb + t) * OF + o] = acc1[t];
    xw2h[(size_t)(nb + t) * OF + o] = f2bf_rne(acc2[t]);
    float v1 = acc1[t] * av, v2 = acc2[t] * av;
    for (int off = 32; off > 0; off >>= 1) {
      v1 += __shfl_down(v1, off, 64);
      v2 += __shfl_down(v2, off, 64);
    }
    if (ln == 0) { red[0][wv][t] = v1; red[1][wv][t] = v2; }
  }
  __syncthreads();
  if (o < 8) {
    p1[nb + o] = red[0][0][o] + red[0][1][o];
    p2[nb + o] = red[1][0][o] + red[1][1][o];
  }
}

// hierarchical scan, phase A: coalesced per-tile exclusive scan + tile sums
__global__ void k_scanA(const int* __restrict__ cnt, int* __restrict__ roff,
                        int* __restrict__ tsum) {
  __shared__ int sh[TS];
  int b = blockIdx.x, t = threadIdx.x;
  int i = b * TS + t;
  int v = (i < NN) ? cnt[i] : 0;
  sh[t] = v;
  __syncthreads();
  for (int off = 1; off < TS; off <<= 1) {
    int u = (t >= off) ? sh[t - off] : 0;
    __syncthreads();
    sh[t] += u;
    __syncthreads();
  }
  if (i < NN) roff[i] = sh[t] - v;  // exclusive within tile
  if (t == TS - 1) tsum[b] = sh[t];
}

// phase B: every block redundantly LDS-scans the 196 tile sums, adds its
// tile offset, and writes roff (+cur copy); last block sets roff[NN]=NE.
__global__ void k_scanB(const int* __restrict__ tsum, int* __restrict__ roff,
                        int* __restrict__ cur) {
  __shared__ int sh[256];
  int b = blockIdx.x, t = threadIdx.x;
  sh[t] = (t < NT) ? tsum[t] : 0;
  __syncthreads();
  for (int off = 1; off < 256; off <<= 1) {
    int u = (t >= off) ? sh[t - off] : 0;
    __syncthreads();
    sh[t] += u;
    __syncthreads();
  }
  int toff = (b == 0) ? 0 : sh[b - 1];
  int i = b * TS + t;
  if (i < NN) {
    int r = roff[i] + toff;
    roff[i] = r;
    cur[i] = r;
  }
  if (b == NT - 1 && t == 0) roff[NN] = NE;
}

// scatter, 16 lanes per edge: lane0 claims CSR slot + writes (dst, p2[dst]);
// all 16 lanes copy the edge's ete row (fp32 256B coalesced read) into
// ete_csr[pos] as bf16 (128B write). After this the gather's ete reads are
// fully SEQUENTIAL (CSR rows in order) instead of random 256B fp32 rows.
__global__ void k_scatter(const int* __restrict__ ei, const float* __restrict__ p2,
                          const float* __restrict__ ete, int* __restrict__ cur,
                          unsigned short* __restrict__ ete_csr,
                          int2* __restrict__ dpv) {
  int grp = threadIdx.x >> 4, l16 = threadIdx.x & 15;
  int e = blockIdx.x * 16 + grp;  // grid*16 == NE exactly
  int pos = 0;
  if (l16 == 0) {
    int dst = ei[NE + e];
    pos = atomicAdd(cur + ei[e], 1);
    dpv[pos] = make_int2(dst, __float_as_int(p2[dst]));
  }
  pos = __shfl(pos, 0, 16);
  float4 t4 = ((const float4*)(ete + (size_t)e * NR))[l16];
  ushort4 h;
  h.x = f2bf_rne(t4.x); h.y = f2bf_rne(t4.y);
  h.z = f2bf_rne(t4.z); h.w = f2bf_rne(t4.w);
  *(ushort4*)(ete_csr + (size_t)pos * NR + l16 * 4) = h;
}

// per-node gather: TWO nodes per wave (round-10 proven structure). ete rows
// now bf16 in CSR order -> row index is wave-uniform (SALU), loads are
// sequential 128B; no edge-id shfl needed. Masked lanes carry pv=-inf ->
// ev=0; row index clamped to 0 when a stream runs past NE (other-node /
// pad rows are finite so no NaN leaks through the ev=0 mask).
__global__ void k_gather(const int2* __restrict__ dpv, const int* __restrict__ roff,
                         const unsigned short* __restrict__ ete_csr,
                         const unsigned short* __restrict__ xw2h,
                         const float* __restrict__ q3, const float* __restrict__ p1,
                         float* __restrict__ g, float* __restrict__ out,
                         float* __restrict__ s) {
  int wv = blockIdx.x * 4 + (threadIdx.x >> 6);  // wave id; grid exact
  int nA = wv * 2, nB = nA + 1;
  int l = threadIdx.x & 63;
  float q3l = q3[l];
  int begA = roff[nA], endA = roff[nA + 1], endB = roff[nB + 1];
  float p1A = p1[nA], p1B = p1[nB];
  float ssA = 0.f, gaA = 0.f, oA0 = 0.f, oA1 = 0.f;
  float ssB = 0.f, gaB = 0.f, oB0 = 0.f, oB1 = 0.f;
  int jbA = begA, jbB = endA;  // begB == endA (CSR contiguity)
  while (jbA < endA || jbB < endB) {
    int dA_ = 0, dB_ = 0;
    float pvA = -INFINITY, pvB = -INFINITY;
    if (jbA + l < endA) { int2 dp = dpv[jbA + l]; dA_ = dp.x; pvA = __int_as_float(dp.y); }
    if (jbB + l < endB) { int2 dp = dpv[jbB + l]; dB_ = dp.x; pvB = __int_as_float(dp.y); }
    int mA = endA - jbA; mA = mA < 0 ? 0 : (mA > 64 ? 64 : mA);
    int mB = endB - jbB; mB = mB < 0 ? 0 : (mB > 64 ? 64 : mB);
    int mm = mA > mB ? mA : mB;
    for (int jj = 0; jj < mm; jj += 4) {
#pragma unroll
      for (int q = 0; q < 4; ++q) {
        // row indices are wave-uniform; clamp keeps them in [0, NE+64)
        int rA = jbA + jj + q; rA = rA < NE ? rA : 0;
        int rB = jbB + jj + q; rB = rB < NE ? rB : 0;
        int dA = __shfl(dA_, jj + q, 64);
        float pA = __shfl(pvA, jj + q, 64);
        int dB = __shfl(dB_, jj + q, 64);
        float pB = __shfl(pvB, jj + q, 64);
        float tA = bf2f(ete_csr[(size_t)rA * NR + l]);
        float tB = bf2f(ete_csr[(size_t)rB * NR + l]);
        unsigned uA = *(const unsigned*)(xw2h + (size_t)dA * OF + 2 * l);
        unsigned uB = *(const unsigned*)(xw2h + (size_t)dB * OF + 2 * l);
        float xA0 = __uint_as_float(uA << 16);
        float xA1 = __uint_as_float(uA & 0xFFFF0000u);
        float xB0 = __uint_as_float(uB << 16);
        float xB1 = __uint_as_float(uB & 0xFFFF0000u);
        float dsA = tA * q3l, dsB = tB * q3l;
        dsA += __shfl_xor(dsA, 1, 64);  dsB += __shfl_xor(dsB, 1, 64);
        dsA += __shfl_xor(dsA, 2, 64);  dsB += __shfl_xor(dsB, 2, 64);
        dsA += __shfl_xor(dsA, 4, 64);  dsB += __shfl_xor(dsB, 4, 64);
        dsA += __shfl_xor(dsA, 8, 64);  dsB += __shfl_xor(dsB, 8, 64);
        dsA += __shfl_xor(dsA, 16, 64); dsB += __shfl_xor(dsB, 16, 64);
        dsA += __shfl_xor(dsA, 32, 64); dsB += __shfl_xor(dsB, 32, 64);
        float vA = p1A + pA + dsA;
        float vB = p1B + pB + dsB;
        vA = vA > 0.f ? vA : 0.2f * vA;
        vB = vB > 0.f ? vB : 0.2f * vB;
        float eVA = __expf(vA);
        float eVB = __expf(vB);
        ssA += eVA;               ssB += eVB;
        gaA = fmaf(eVA, tA, gaA); gaB = fmaf(eVB, tB, gaB);
        oA0 = fmaf(eVA, xA0, oA0); oB0 = fmaf(eVB, xB0, oB0);
        oA1 = fmaf(eVA, xA1, oA1); oB1 = fmaf(eVB, xB1, oB1);
      }
    }
    jbA += 64; jbB += 64;
  }
  float invA = 1.f / (ssA + 1e-16f);
  float invB = 1.f / (ssB + 1e-16f);
  g[(size_t)nA * NR + l] = gaA * invA;
  g[(size_t)nB * NR + l] = gaB * invB;
  *(float2*)(out + (size_t)nA * OF + 2 * l) = make_float2(oA0 * invA, oA1 * invA);
  *(float2*)(out + (size_t)nB * OF + 2 * l) = make_float2(oB0 * invB, oB1 * invB);
  if (l == 0) { s[nA] = ssA; s[nB] = ssB; }
}

// finalize: out = elu( (s/(s+1e-16))*xW1 + out + g@W3 ), 8 nodes/block.
// Separate kernel (round-11 lesson: wave-local shfl-broadcast GEMM costs
// ~2.5x more than this shared-LDS form amortizing W3 over 8 nodes).
__global__ void k_final(const float* __restrict__ xW1, const float* __restrict__ g,
                        const float* __restrict__ s, const float* __restrict__ W,
                        float* __restrict__ out) {
  __shared__ float gs[8 * NR];
  int nb = blockIdx.x * 8;
  int o = threadIdx.x;  // 0..127
  for (int i = o; i < 8 * NR; i += 128) gs[i] = g[(size_t)nb * NR + i];
  __syncthreads();
  float acc[8] = {0.f, 0.f, 0.f, 0.f, 0.f, 0.f, 0.f, 0.f};
  for (int d = 0; d < NR; ++d) {
    float w3 = W[(size_t)(2 * INF_ + d) * OF + o];
#pragma unroll
    for (int t = 0; t < 8; ++t) acc[t] = fmaf(gs[t * NR + d], w3, acc[t]);
  }
#pragma unroll
  for (int t = 0; t < 8; ++t) {
    int n = nb + t;
    float sv = s[n];
    float sa = sv > 0.f ? sv / (sv + 1e-16f) : 0.f;
    float v = sa * xW1[(size_t)n * OF + o] + out[(size_t)n * OF + o] + acc[t];
    out[(size_t)n * OF + o] = v > 0.f ? v : expm1f(v);
  }
}

extern "C" void kernel_launch(void* const* d_in, const int* in_sizes, int n_in,
                              void* d_out, int out_size, void* d_ws, size_t ws_size,
                              hipStream_t stream) {
  const int* ei = (const int*)d_in[0];
  const float* x = (const float*)d_in[1];
  const float* ete = (const float*)d_in[2];
  const float* W = (const float*)d_in[3];
  const float* a = (const float*)d_in[4];
  float* out = (float*)d_out;

  float* ws = (float*)d_ws;
  float* xW1 = ws;                                        // N*128 fp32 (6.4M words)
  unsigned short* xw2h = (unsigned short*)(xW1 + (size_t)NN * OF);  // N*128 bf16
  unsigned short* ete_csr = xw2h + (size_t)NN * OF;       // (NE+64) rows x 64 bf16
  int2* dpv = (int2*)(ete_csr + (size_t)(NE + 64) * NR);  // E x (dst, p2bits)
  float* g = (float*)(dpv + NE);                          // N*64
  float* p1 = g + (size_t)NN * NR;                        // N
  float* p2 = p1 + NN;                                    // N
  float* q3 = p2 + NN;                                    // 64
  int* cnt = (int*)(q3 + NR);                             // N
  int* roff = cnt + NN;                                   // N+1
  int* cur = roff + NN + 1;                               // N
  int* tsum = cur + NN;                                   // 256
  float* s = (float*)(tsum + 256);                        // N
  // total ~40.4M words = 162 MB (ws ~819 MB per harness poison fill)

  k_init<<<(NN + 255) / 256, 256, 0, stream>>>(W, a, q3, cnt,
                                               (unsigned*)(ete_csr + (size_t)NE * NR));
  k_node_pre<<<NN / 8, 128, 0, stream>>>(x, W, a, ei, xW1, xw2h, p1, p2, cnt);
  k_scanA<<<NT, TS, 0, stream>>>(cnt, roff, tsum);
  k_scanB<<<NT, 256, 0, stream>>>(tsum, roff, cur);
  k_scatter<<<NE / 16, 256, 0, stream>>>(ei, p2, ete, cur, ete_csr, dpv);
  k_gather<<<NN / 8, 256, 0, stream>>>(dpv, roff, ete_csr, xw2h, q3, p1, g, out, s);
  k_final<<<NN / 8, 128, 0, stream>>>(xW1, g, s, W, out);
}

// Round 13
// 292.950 us; speedup vs baseline: 1.0342x; 1.0342x over previous
//
#include <hip/hip_runtime.h>
#include <cmath>

#define NN 50000
#define NE 800000
#define INF_ 128
#define NR 64
#define OF 128
#define TS 256
#define NT ((NN + TS - 1) / TS)  // 196 tiles

__device__ __forceinline__ unsigned short f2bf_rne(float f) {
  unsigned u = __float_as_uint(f);
  u += 0x7FFFu + ((u >> 16) & 1u);  // round-to-nearest-even
  return (unsigned short)(u >> 16);
}
__device__ __forceinline__ float bf2f(unsigned short h) {
  return __uint_as_float(((unsigned)h) << 16);
}

// zero cnt[]; block 0 also computes q3[d] = sum_j W[(256+d),j] * a[j]
__global__ void k_init(const float* __restrict__ W, const float* __restrict__ a,
                       float* __restrict__ q3, int* __restrict__ cnt) {
  int i = blockIdx.x * 256 + threadIdx.x;
  if (i < NN) cnt[i] = 0;
  if (blockIdx.x == 0 && threadIdx.x < NR) {
    const float* row = W + (size_t)(2 * INF_ + threadIdx.x) * OF;
    float acc = 0.f;
    for (int j = 0; j < OF; ++j) acc = fmaf(row[j], a[j], acc);
    q3[threadIdx.x] = acc;
  }
}

// per-node precompute: xW1 = x@W1 (fp32), xw2h = x@W2 (bf16), p1, p2.
// Fused: src-degree histogram (grid*block == NE exactly, one edge per thread).
__global__ void k_node_pre(const float* __restrict__ x, const float* __restrict__ W,
                           const float* __restrict__ a, const int* __restrict__ ei,
                           float* __restrict__ xW1, unsigned short* __restrict__ xw2h,
                           float* __restrict__ p1, float* __restrict__ p2,
                           int* __restrict__ cnt) {
  int gid = blockIdx.x * 128 + threadIdx.x;  // 0..799999 == edge id
  atomicAdd(cnt + ei[gid], 1);
  __shared__ float xs[8][INF_];
  __shared__ float red[2][2][8];
  int nb = blockIdx.x * 8;
  int o = threadIdx.x;  // 0..127
  for (int t = 0; t < 8; ++t) xs[t][o] = x[(size_t)(nb + t) * INF_ + o];
  __syncthreads();
  float acc1[8] = {0.f, 0.f, 0.f, 0.f, 0.f, 0.f, 0.f, 0.f};
  float acc2[8] = {0.f, 0.f, 0.f, 0.f, 0.f, 0.f, 0.f, 0.f};
  for (int k = 0; k < INF_; ++k) {
    float w1 = W[(size_t)k * OF + o];
    float w2 = W[(size_t)(INF_ + k) * OF + o];
#pragma unroll
    for (int t = 0; t < 8; ++t) {
      acc1[t] = fmaf(xs[t][k], w1, acc1[t]);
      acc2[t] = fmaf(xs[t][k], w2, acc2[t]);
    }
  }
  float av = a[o];
  int wv = o >> 6, ln = o & 63;
#pragma unroll
  for (int t = 0; t < 8; ++t) {
    xW1[(size_t)(nb + t) * OF + o] = acc1[t];
    xw2h[(size_t)(nb + t) * OF + o] = f2bf_rne(acc2[t]);
    float v1 = acc1[t] * av, v2 = acc2[t] * av;
    for (int off = 32; off > 0; off >>= 1) {
      v1 += __shfl_down(v1, off, 64);
      v2 += __shfl_down(v2, off, 64);
    }
    if (ln == 0) { red[0][wv][t] = v1; red[1][wv][t] = v2; }
  }
  __syncthreads();
  if (o < 8) {
    p1[nb + o] = red[0][0][o] + red[0][1][o];
    p2[nb + o] = red[1][0][o] + red[1][1][o];
  }
}

// hierarchical scan, phase A: coalesced per-tile exclusive scan + tile sums
__global__ void k_scanA(const int* __restrict__ cnt, int* __restrict__ roff,
                        int* __restrict__ tsum) {
  __shared__ int sh[TS];
  int b = blockIdx.x, t = threadIdx.x;
  int i = b * TS + t;
  int v = (i < NN) ? cnt[i] : 0;
  sh[t] = v;
  __syncthreads();
  for (int off = 1; off < TS; off <<= 1) {
    int u = (t >= off) ? sh[t - off] : 0;
    __syncthreads();
    sh[t] += u;
    __syncthreads();
  }
  if (i < NN) roff[i] = sh[t] - v;  // exclusive within tile
  if (t == TS - 1) tsum[b] = sh[t];
}

// phase B: every block redundantly LDS-scans the 196 tile sums, adds its
// tile offset, and writes roff (+cur copy); last block sets roff[NN]=NE.
__global__ void k_scanB(const int* __restrict__ tsum, int* __restrict__ roff,
                        int* __restrict__ cur) {
  __shared__ int sh[256];
  int b = blockIdx.x, t = threadIdx.x;
  sh[t] = (t < NT) ? tsum[t] : 0;
  __syncthreads();
  for (int off = 1; off < 256; off <<= 1) {
    int u = (t >= off) ? sh[t - off] : 0;
    __syncthreads();
    sh[t] += u;
    __syncthreads();
  }
  int toff = (b == 0) ? 0 : sh[b - 1];
  int i = b * TS + t;
  if (i < NN) {
    int r = roff[i] + toff;
    roff[i] = r;
    cur[i] = r;
  }
  if (b == NT - 1 && t == 0) roff[NN] = NE;
}

// scatter, 16 lanes per edge. Reads ete sequentially (edge order); computes
// the FULL softmax numerator here: d = ete·q3 (16-lane butterfly), then
// ev = exp(leaky_relu(p1[src]+p2[dst]+d)) on lane 0. Writes (dst, ev) to the
// CSR slot and the ete row as bf16 to ete_csr. After this pass the gather
// needs NO cross-lane ops at all (round-12 lesson: 9 ds_bpermute/edge made
// the gather LDS-pipe-bound at ~70us of serialized LDS time).
__global__ void k_scatter(const int* __restrict__ ei, const float* __restrict__ p1,
                          const float* __restrict__ p2, const float* __restrict__ q3,
                          const float* __restrict__ ete, int* __restrict__ cur,
                          unsigned short* __restrict__ ete_csr,
                          int2* __restrict__ dpv) {
  int grp = threadIdx.x >> 4, l16 = threadIdx.x & 15;
  int e = blockIdx.x * 16 + grp;  // grid*16 == NE exactly
  float4 t4 = ((const float4*)(ete + (size_t)e * NR))[l16];
  float4 q4 = ((const float4*)q3)[l16];
  float dd = t4.x * q4.x + t4.y * q4.y + t4.z * q4.z + t4.w * q4.w;
  dd += __shfl_xor(dd, 8, 16);
  dd += __shfl_xor(dd, 4, 16);
  dd += __shfl_xor(dd, 2, 16);
  dd += __shfl_xor(dd, 1, 16);
  int pos = 0;
  if (l16 == 0) {
    int src = ei[e], dst = ei[NE + e];
    pos = atomicAdd(cur + src, 1);
    float v = p1[src] + p2[dst] + dd;
    v = v > 0.f ? v : 0.2f * v;
    dpv[pos] = make_int2(dst, __float_as_int(__expf(v)));
  }
  pos = __shfl(pos, 0, 16);
  ushort4 h;
  h.x = f2bf_rne(t4.x); h.y = f2bf_rne(t4.y);
  h.z = f2bf_rne(t4.z); h.w = f2bf_rne(t4.w);
  *(ushort4*)(ete_csr + (size_t)pos * NR + l16 * 4) = h;
}

// per-node gather: TWO nodes per wave, ZERO cross-lane ops. Per edge:
// (dst, ev) via wave-uniform 8B load (one L1-hit transaction, broadcast by
// HW); ete_csr row sequential bf16 128B; xw2h row L2-resident. ssum += ev is
// wave-uniform so no final reduction. Masked slots (stream ran past its end)
// select ev=0 and clamp the row index to 0 (reads stay in-bounds; x*0=0).
__global__ void k_gather(const int2* __restrict__ dpv, const int* __restrict__ roff,
                         const unsigned short* __restrict__ ete_csr,
                         const unsigned short* __restrict__ xw2h,
                         float* __restrict__ g, float* __restrict__ out,
                         float* __restrict__ s) {
  int wv = blockIdx.x * 4 + (threadIdx.x >> 6);  // wave id; grid exact
  int nA = wv * 2, nB = nA + 1;
  int l = threadIdx.x & 63;
  int begA = roff[nA], endA = roff[nA + 1], endB = roff[nB + 1];
  float ssA = 0.f, gaA = 0.f, oA0 = 0.f, oA1 = 0.f;
  float ssB = 0.f, gaB = 0.f, oB0 = 0.f, oB1 = 0.f;
  int jbA = begA, jbB = endA;  // begB == endA (CSR contiguity)
  while (jbA < endA || jbB < endB) {
    int mA = endA - jbA; mA = mA < 0 ? 0 : (mA > 64 ? 64 : mA);
    int mB = endB - jbB; mB = mB < 0 ? 0 : (mB > 64 ? 64 : mB);
    int mm = mA > mB ? mA : mB;
    for (int jj = 0; jj < mm; jj += 4) {
#pragma unroll
      for (int q = 0; q < 4; ++q) {
        int rA = jbA + jj + q, rB = jbB + jj + q;
        bool okA = rA < endA, okB = rB < endB;
        int rAc = okA ? rA : 0, rBc = okB ? rB : 0;
        int2 dpA = dpv[rAc];  // wave-uniform address -> 1 transaction
        int2 dpB = dpv[rBc];
        float evA = okA ? __int_as_float(dpA.y) : 0.f;
        float evB = okB ? __int_as_float(dpB.y) : 0.f;
        float tA = bf2f(ete_csr[(size_t)rAc * NR + l]);
        float tB = bf2f(ete_csr[(size_t)rBc * NR + l]);
        unsigned uA = *(const unsigned*)(xw2h + (size_t)dpA.x * OF + 2 * l);
        unsigned uB = *(const unsigned*)(xw2h + (size_t)dpB.x * OF + 2 * l);
        float xA0 = __uint_as_float(uA << 16);
        float xA1 = __uint_as_float(uA & 0xFFFF0000u);
        float xB0 = __uint_as_float(uB << 16);
        float xB1 = __uint_as_float(uB & 0xFFFF0000u);
        ssA += evA;                ssB += evB;
        gaA = fmaf(evA, tA, gaA);  gaB = fmaf(evB, tB, gaB);
        oA0 = fmaf(evA, xA0, oA0); oB0 = fmaf(evB, xB0, oB0);
        oA1 = fmaf(evA, xA1, oA1); oB1 = fmaf(evB, xB1, oB1);
      }
    }
    jbA += 64; jbB += 64;
  }
  float invA = 1.f / (ssA + 1e-16f);
  float invB = 1.f / (ssB + 1e-16f);
  g[(size_t)nA * NR + l] = gaA * invA;
  g[(size_t)nB * NR + l] = gaB * invB;
  *(float2*)(out + (size_t)nA * OF + 2 * l) = make_float2(oA0 * invA, oA1 * invA);
  *(float2*)(out + (size_t)nB * OF + 2 * l) = make_float2(oB0 * invB, oB1 * invB);
  if (l == 0) { s[nA] = ssA; s[nB] = ssB; }
}

// finalize: out = elu( (s/(s+1e-16))*xW1 + out + g@W3 ), 8 nodes/block.
// Separate kernel (round-11 lesson: wave-local shfl-broadcast GEMM costs
// ~2.5x more than this shared-LDS form amortizing W3 over 8 nodes).
__global__ void k_final(const float* __restrict__ xW1, const float* __restrict__ g,
                        const float* __restrict__ s, const float* __restrict__ W,
                        float* __restrict__ out) {
  __shared__ float gs[8 * NR];
  int nb = blockIdx.x * 8;
  int o = threadIdx.x;  // 0..127
  for (int i = o; i < 8 * NR; i += 128) gs[i] = g[(size_t)nb * NR + i];
  __syncthreads();
  float acc[8] = {0.f, 0.f, 0.f, 0.f, 0.f, 0.f, 0.f, 0.f};
  for (int d = 0; d < NR; ++d) {
    float w3 = W[(size_t)(2 * INF_ + d) * OF + o];
#pragma unroll
    for (int t = 0; t < 8; ++t) acc[t] = fmaf(gs[t * NR + d], w3, acc[t]);
  }
#pragma unroll
  for (int t = 0; t < 8; ++t) {
    int n = nb + t;
    float sv = s[n];
    float sa = sv > 0.f ? sv / (sv + 1e-16f) : 0.f;
    float v = sa * xW1[(size_t)n * OF + o] + out[(size_t)n * OF + o] + acc[t];
    out[(size_t)n * OF + o] = v > 0.f ? v : expm1f(v);
  }
}

extern "C" void kernel_launch(void* const* d_in, const int* in_sizes, int n_in,
                              void* d_out, int out_size, void* d_ws, size_t ws_size,
                              hipStream_t stream) {
  const int* ei = (const int*)d_in[0];
  const float* x = (const float*)d_in[1];
  const float* ete = (const float*)d_in[2];
  const float* W = (const float*)d_in[3];
  const float* a = (const float*)d_in[4];
  float* out = (float*)d_out;

  float* ws = (float*)d_ws;
  float* xW1 = ws;                                        // N*128 fp32 (6.4M words)
  unsigned short* xw2h = (unsigned short*)(xW1 + (size_t)NN * OF);  // N*128 bf16 (3.2M words)
  unsigned short* ete_csr = xw2h + (size_t)NN * OF;       // NE rows x 64 bf16 (25.6M words)
  int2* dpv = (int2*)(ete_csr + (size_t)NE * NR);         // E x (dst, ev_bits), 8B-aligned
  float* g = (float*)(dpv + NE);                          // N*64
  float* p1 = g + (size_t)NN * NR;                        // N
  float* p2 = p1 + NN;                                    // N
  float* q3 = p2 + NN;                                    // 64
  int* cnt = (int*)(q3 + NR);                             // N
  int* roff = cnt + NN;                                   // N+1
  int* cur = roff + NN + 1;                               // N
  int* tsum = cur + NN;                                   // 256
  float* s = (float*)(tsum + 256);                        // N
  // total ~40.3M words = 161 MB (ws ~819 MB)

  k_init<<<(NN + 255) / 256, 256, 0, stream>>>(W, a, q3, cnt);
  k_node_pre<<<NN / 8, 128, 0, stream>>>(x, W, a, ei, xW1, xw2h, p1, p2, cnt);
  k_scanA<<<NT, TS, 0, stream>>>(cnt, roff, tsum);
  k_scanB<<<NT, 256, 0, stream>>>(tsum, roff, cur);
  k_scatter<<<NE / 16, 256, 0, stream>>>(ei, p1, p2, q3, ete, cur, ete_csr, dpv);
  k_gather<<<NN / 8, 256, 0, stream>>>(dpv, roff, ete_csr, xw2h, g, out, s);
  k_final<<<NN / 8, 128, 0, stream>>>(xW1, g, s, W, out);
}

// Round 14
// 282.983 us; speedup vs baseline: 1.0706x; 1.0352x over previous
//
#include <hip/hip_runtime.h>
#include <cmath>

#define NN 50000
#define NE 800000
#define INF_ 128
#define NR 64
#define OF 128
#define TS 256
#define NT ((NN + TS - 1) / TS)  // 196 tiles

__device__ __forceinline__ unsigned short f2bf_rne(float f) {
  unsigned u = __float_as_uint(f);
  u += 0x7FFFu + ((u >> 16) & 1u);  // round-to-nearest-even
  return (unsigned short)(u >> 16);
}
__device__ __forceinline__ float bf2f(unsigned short h) {
  return __uint_as_float(((unsigned)h) << 16);
}

// zero cnt[]; block 0 also computes q3[d] = sum_j W[(256+d),j] * a[j]
__global__ void k_init(const float* __restrict__ W, const float* __restrict__ a,
                       float* __restrict__ q3, int* __restrict__ cnt) {
  int i = blockIdx.x * 256 + threadIdx.x;
  if (i < NN) cnt[i] = 0;
  if (blockIdx.x == 0 && threadIdx.x < NR) {
    const float* row = W + (size_t)(2 * INF_ + threadIdx.x) * OF;
    float acc = 0.f;
    for (int j = 0; j < OF; ++j) acc = fmaf(row[j], a[j], acc);
    q3[threadIdx.x] = acc;
  }
}

// per-node precompute: xw1h = x@W1 (bf16), xw2h = x@W2 (bf16), p1, p2.
// 16 nodes/block as two independent 8-node halves (256 threads): each
// block's W1/W2 column stream serves 16 nodes (halves per-node L2 traffic).
// Fused: src-degree histogram (grid*block == NE exactly).
__global__ void k_node_pre(const float* __restrict__ x, const float* __restrict__ W,
                           const float* __restrict__ a, const int* __restrict__ ei,
                           unsigned short* __restrict__ xw1h,
                           unsigned short* __restrict__ xw2h,
                           float* __restrict__ p1, float* __restrict__ p2,
                           int* __restrict__ cnt) {
  int tid = threadIdx.x;                 // 0..255
  int gid = blockIdx.x * 256 + tid;      // 0..799999 == edge id
  atomicAdd(cnt + ei[gid], 1);
  __shared__ float xs[16][INF_];
  __shared__ float red[2][4][8];
  int half = tid >> 7;                   // 0/1
  int o = tid & 127;
  int nb = blockIdx.x * 16 + half * 8;   // this half's 8 nodes
  for (int t = 0; t < 8; ++t)
    xs[half * 8 + t][o] = x[(size_t)(nb + t) * INF_ + o];
  __syncthreads();
  float acc1[8] = {0.f, 0.f, 0.f, 0.f, 0.f, 0.f, 0.f, 0.f};
  float acc2[8] = {0.f, 0.f, 0.f, 0.f, 0.f, 0.f, 0.f, 0.f};
  for (int k = 0; k < INF_; ++k) {
    float w1 = W[(size_t)k * OF + o];
    float w2 = W[(size_t)(INF_ + k) * OF + o];
#pragma unroll
    for (int t = 0; t < 8; ++t) {
      acc1[t] = fmaf(xs[half * 8 + t][k], w1, acc1[t]);
      acc2[t] = fmaf(xs[half * 8 + t][k], w2, acc2[t]);
    }
  }
  float av = a[o];
  int wvh = (tid >> 6) & 1;  // wave within half
  int ln = tid & 63;
#pragma unroll
  for (int t = 0; t < 8; ++t) {
    xw1h[(size_t)(nb + t) * OF + o] = f2bf_rne(acc1[t]);
    xw2h[(size_t)(nb + t) * OF + o] = f2bf_rne(acc2[t]);
    float v1 = acc1[t] * av, v2 = acc2[t] * av;
    for (int off = 32; off > 0; off >>= 1) {
      v1 += __shfl_down(v1, off, 64);
      v2 += __shfl_down(v2, off, 64);
    }
    if (ln == 0) { red[0][half * 2 + wvh][t] = v1; red[1][half * 2 + wvh][t] = v2; }
  }
  __syncthreads();
  if (tid < 8) {
    p1[blockIdx.x * 16 + tid] = red[0][0][tid] + red[0][1][tid];
    p2[blockIdx.x * 16 + tid] = red[1][0][tid] + red[1][1][tid];
  } else if (tid >= 128 && tid < 136) {
    int t = tid - 128;
    p1[blockIdx.x * 16 + 8 + t] = red[0][2][t] + red[0][3][t];
    p2[blockIdx.x * 16 + 8 + t] = red[1][2][t] + red[1][3][t];
  }
}

// hierarchical scan, phase A: coalesced per-tile exclusive scan + tile sums
__global__ void k_scanA(const int* __restrict__ cnt, int* __restrict__ roff,
                        int* __restrict__ tsum) {
  __shared__ int sh[TS];
  int b = blockIdx.x, t = threadIdx.x;
  int i = b * TS + t;
  int v = (i < NN) ? cnt[i] : 0;
  sh[t] = v;
  __syncthreads();
  for (int off = 1; off < TS; off <<= 1) {
    int u = (t >= off) ? sh[t - off] : 0;
    __syncthreads();
    sh[t] += u;
    __syncthreads();
  }
  if (i < NN) roff[i] = sh[t] - v;  // exclusive within tile
  if (t == TS - 1) tsum[b] = sh[t];
}

// phase B: every block redundantly LDS-scans the 196 tile sums, adds its
// tile offset, and writes roff (+cur copy); last block sets roff[NN]=NE.
__global__ void k_scanB(const int* __restrict__ tsum, int* __restrict__ roff,
                        int* __restrict__ cur) {
  __shared__ int sh[256];
  int b = blockIdx.x, t = threadIdx.x;
  sh[t] = (t < NT) ? tsum[t] : 0;
  __syncthreads();
  for (int off = 1; off < 256; off <<= 1) {
    int u = (t >= off) ? sh[t - off] : 0;
    __syncthreads();
    sh[t] += u;
    __syncthreads();
  }
  int toff = (b == 0) ? 0 : sh[b - 1];
  int i = b * TS + t;
  if (i < NN) {
    int r = roff[i] + toff;
    roff[i] = r;
    cur[i] = r;
  }
  if (b == NT - 1 && t == 0) roff[NN] = NE;
}

// scatter, 16 lanes per edge: d = ete·q3 (16-lane butterfly), lane0 computes
// ev = exp(leaky_relu(p1[src]+p2[dst]+d)) and writes (dst, ev) to the CSR
// slot; all lanes copy the ete row to ete_csr as bf16 (sequential-read,
// random full-128B-row write).
__global__ void k_scatter(const int* __restrict__ ei, const float* __restrict__ p1,
                          const float* __restrict__ p2, const float* __restrict__ q3,
                          const float* __restrict__ ete, int* __restrict__ cur,
                          unsigned short* __restrict__ ete_csr,
                          int2* __restrict__ dpv) {
  int grp = threadIdx.x >> 4, l16 = threadIdx.x & 15;
  int e = blockIdx.x * 16 + grp;  // grid*16 == NE exactly
  float4 t4 = ((const float4*)(ete + (size_t)e * NR))[l16];
  float4 q4 = ((const float4*)q3)[l16];
  float dd = t4.x * q4.x + t4.y * q4.y + t4.z * q4.z + t4.w * q4.w;
  dd += __shfl_xor(dd, 8, 16);
  dd += __shfl_xor(dd, 4, 16);
  dd += __shfl_xor(dd, 2, 16);
  dd += __shfl_xor(dd, 1, 16);
  int pos = 0;
  if (l16 == 0) {
    int src = ei[e], dst = ei[NE + e];
    pos = atomicAdd(cur + src, 1);
    float v = p1[src] + p2[dst] + dd;
    v = v > 0.f ? v : 0.2f * v;
    dpv[pos] = make_int2(dst, __float_as_int(__expf(v)));
  }
  pos = __shfl(pos, 0, 16);
  ushort4 h;
  h.x = f2bf_rne(t4.x); h.y = f2bf_rne(t4.y);
  h.z = f2bf_rne(t4.z); h.w = f2bf_rne(t4.w);
  *(ushort4*)(ete_csr + (size_t)pos * NR + l16 * 4) = h;
}

// per-node gather: TWO nodes per wave, ZERO cross-lane ops (round-12 lesson).
// Per edge: (dst, ev) via wave-uniform 8B load; ete_csr row sequential bf16;
// xw2h row L2/L3-resident. Outputs normalized g (bf16) and o (packed bf16
// pair per lane) — k_final assembles fp32 out exactly once.
__global__ void k_gather(const int2* __restrict__ dpv, const int* __restrict__ roff,
                         const unsigned short* __restrict__ ete_csr,
                         const unsigned short* __restrict__ xw2h,
                         unsigned short* __restrict__ gh,
                         unsigned* __restrict__ obuf, float* __restrict__ s) {
  int wv = blockIdx.x * 4 + (threadIdx.x >> 6);  // wave id; grid exact
  int nA = wv * 2, nB = nA + 1;
  int l = threadIdx.x & 63;
  int begA = roff[nA], endA = roff[nA + 1], endB = roff[nB + 1];
  float ssA = 0.f, gaA = 0.f, oA0 = 0.f, oA1 = 0.f;
  float ssB = 0.f, gaB = 0.f, oB0 = 0.f, oB1 = 0.f;
  int jbA = begA, jbB = endA;  // begB == endA (CSR contiguity)
  while (jbA < endA || jbB < endB) {
    int mA = endA - jbA; mA = mA < 0 ? 0 : (mA > 64 ? 64 : mA);
    int mB = endB - jbB; mB = mB < 0 ? 0 : (mB > 64 ? 64 : mB);
    int mm = mA > mB ? mA : mB;
    for (int jj = 0; jj < mm; jj += 4) {
#pragma unroll
      for (int q = 0; q < 4; ++q) {
        int rA = jbA + jj + q, rB = jbB + jj + q;
        bool okA = rA < endA, okB = rB < endB;
        int rAc = okA ? rA : 0, rBc = okB ? rB : 0;
        int2 dpA = dpv[rAc];  // wave-uniform address -> 1 transaction
        int2 dpB = dpv[rBc];
        float evA = okA ? __int_as_float(dpA.y) : 0.f;
        float evB = okB ? __int_as_float(dpB.y) : 0.f;
        float tA = bf2f(ete_csr[(size_t)rAc * NR + l]);
        float tB = bf2f(ete_csr[(size_t)rBc * NR + l]);
        unsigned uA = *(const unsigned*)(xw2h + (size_t)dpA.x * OF + 2 * l);
        unsigned uB = *(const unsigned*)(xw2h + (size_t)dpB.x * OF + 2 * l);
        float xA0 = __uint_as_float(uA << 16);
        float xA1 = __uint_as_float(uA & 0xFFFF0000u);
        float xB0 = __uint_as_float(uB << 16);
        float xB1 = __uint_as_float(uB & 0xFFFF0000u);
        ssA += evA;                ssB += evB;
        gaA = fmaf(evA, tA, gaA);  gaB = fmaf(evB, tB, gaB);
        oA0 = fmaf(evA, xA0, oA0); oB0 = fmaf(evB, xB0, oB0);
        oA1 = fmaf(evA, xA1, oA1); oB1 = fmaf(evB, xB1, oB1);
      }
    }
    jbA += 64; jbB += 64;
  }
  float invA = 1.f / (ssA + 1e-16f);
  float invB = 1.f / (ssB + 1e-16f);
  gh[(size_t)nA * NR + l] = f2bf_rne(gaA * invA);
  gh[(size_t)nB * NR + l] = f2bf_rne(gaB * invB);
  obuf[(size_t)nA * NR + l] =
      ((unsigned)f2bf_rne(oA1 * invA) << 16) | (unsigned)f2bf_rne(oA0 * invA);
  obuf[(size_t)nB * NR + l] =
      ((unsigned)f2bf_rne(oB1 * invB) << 16) | (unsigned)f2bf_rne(oB0 * invB);
  if (l == 0) { s[nA] = ssA; s[nB] = ssB; }
}

// finalize: out = elu( sa*xW1 + o + g@W3 ), 8 nodes/block; single fp32 out
// write. Inputs g/xW1/o are bf16 (halved traffic vs round 13).
__global__ void k_final(const unsigned short* __restrict__ xw1h,
                        const unsigned short* __restrict__ gh,
                        const unsigned* __restrict__ obuf,
                        const float* __restrict__ s, const float* __restrict__ W,
                        float* __restrict__ out) {
  __shared__ float gs[8 * NR];
  int nb = blockIdx.x * 8;
  int o = threadIdx.x;  // 0..127
  for (int i = o; i < 8 * NR; i += 128) gs[i] = bf2f(gh[(size_t)nb * NR + i]);
  __syncthreads();
  float acc[8] = {0.f, 0.f, 0.f, 0.f, 0.f, 0.f, 0.f, 0.f};
  for (int d = 0; d < NR; ++d) {
    float w3 = W[(size_t)(2 * INF_ + d) * OF + o];
#pragma unroll
    for (int t = 0; t < 8; ++t) acc[t] = fmaf(gs[t * NR + d], w3, acc[t]);
  }
#pragma unroll
  for (int t = 0; t < 8; ++t) {
    int n = nb + t;
    float sv = s[n];
    float sa = sv > 0.f ? sv / (sv + 1e-16f) : 0.f;
    unsigned ob = obuf[(size_t)n * NR + (o >> 1)];
    float ov = (o & 1) ? __uint_as_float(ob & 0xFFFF0000u)
                       : __uint_as_float(ob << 16);
    float v = fmaf(sa, bf2f(xw1h[(size_t)n * OF + o]), ov + acc[t]);
    out[(size_t)n * OF + o] = v > 0.f ? v : expm1f(v);
  }
}

extern "C" void kernel_launch(void* const* d_in, const int* in_sizes, int n_in,
                              void* d_out, int out_size, void* d_ws, size_t ws_size,
                              hipStream_t stream) {
  const int* ei = (const int*)d_in[0];
  const float* x = (const float*)d_in[1];
  const float* ete = (const float*)d_in[2];
  const float* W = (const float*)d_in[3];
  const float* a = (const float*)d_in[4];
  float* out = (float*)d_out;

  unsigned short* xw1h = (unsigned short*)d_ws;           // N*128 bf16 (12.8 MB)
  unsigned short* xw2h = xw1h + (size_t)NN * OF;          // N*128 bf16 (12.8 MB)
  unsigned short* ete_csr = xw2h + (size_t)NN * OF;       // NE*64 bf16 (102.4 MB)
  int2* dpv = (int2*)(ete_csr + (size_t)NE * NR);         // E x (dst, ev) (6.4 MB, 8B-aligned)
  unsigned short* gh = (unsigned short*)(dpv + NE);       // N*64 bf16 (6.4 MB)
  unsigned* obuf = (unsigned*)(gh + (size_t)NN * NR);     // N*64 packed bf16x2 (12.8 MB)
  float* p1 = (float*)(obuf + (size_t)NN * NR);           // N
  float* p2 = p1 + NN;                                    // N
  float* q3 = p2 + NN;                                    // 64
  int* cnt = (int*)(q3 + NR);                             // N
  int* roff = cnt + NN;                                   // N+1
  int* cur = roff + NN + 1;                               // N
  int* tsum = cur + NN;                                   // 256
  float* s = (float*)(tsum + 256);                        // N
  // total ~155 MB (ws ~819 MB)

  k_init<<<(NN + 255) / 256, 256, 0, stream>>>(W, a, q3, cnt);
  k_node_pre<<<NN / 16, 256, 0, stream>>>(x, W, a, ei, xw1h, xw2h, p1, p2, cnt);
  k_scanA<<<NT, TS, 0, stream>>>(cnt, roff, tsum);
  k_scanB<<<NT, 256, 0, stream>>>(tsum, roff, cur);
  k_scatter<<<NE / 16, 256, 0, stream>>>(ei, p1, p2, q3, ete, cur, ete_csr, dpv);
  k_gather<<<NN / 8, 256, 0, stream>>>(dpv, roff, ete_csr, xw2h, gh, obuf, s);
  k_final<<<NN / 8, 128, 0, stream>>>(xw1h, gh, obuf, s, W, out);
}